// Round 3
// baseline (283.573 us; speedup 1.0000x reference)
//
#include <hip/hip_runtime.h>
#include <hip/hip_bf16.h>
#include <cstdint>

// Problem constants
#define NTOK 8192
#define DIN  1024
#define DOUT 1024
#define NEXP 8

typedef __attribute__((ext_vector_type(8)))  __bf16 bf16x8;
typedef __attribute__((ext_vector_type(4)))  float  f32x4;
typedef __attribute__((ext_vector_type(16))) float  f32x16;

__device__ __forceinline__ unsigned short f2bf(float f) {
    unsigned int u = __builtin_bit_cast(unsigned int, f);
    u += 0x7FFFu + ((u >> 16) & 1u);   // round-to-nearest-even
    return (unsigned short)(u >> 16);
}

__device__ __forceinline__ void cp16(const void* gsrc, void* ldst) {
    __builtin_amdgcn_global_load_lds(
        (const __attribute__((address_space(1))) void*)gsrc,
        (__attribute__((address_space(3))) void*)ldst,
        16, 0, 0);
}

// ---------------------------------------------------------------------------
// Prep kernel (merged so the two memory-bound passes overlap across CUs):
//   blocks [0, 2048):     We [e][k][o] fp32 -> WebT [e][o][k] bf16
//   blocks [2048, 2304):  gate softmax(x@Wg+bg) + x -> bf16
// Gate rewrite rationale (R2): old per-lane Wg float4 loads had 128B lane
// stride -> ~64 cache lines per vector load -> serialized L1 transactions.
// New: Wg transposed into LDS once per block; thread=(token,expert) with
// conflict-free padded float4 LDS reads.
// ---------------------------------------------------------------------------
__global__ __launch_bounds__(256) void prep_kernel(
    const float* __restrict__ x, const float* __restrict__ We,
    const float* __restrict__ Wg, const float* __restrict__ bg,
    unsigned short* __restrict__ xb, unsigned short* __restrict__ wt,
    float* __restrict__ g)
{
    __shared__ float smem[12416];   // 49664 B; conv branch uses 9216 B of it

    int t = threadIdx.x;

    if (blockIdx.x < 2048) {
        // ---- conv_we branch: 64x64 transpose tiles via LDS ----
        unsigned short* tile = (unsigned short*)smem;   // [64][72]
        int b = blockIdx.x;
        int e  = b >> 8;
        int kt = (b >> 4) & 15;
        int ot = b & 15;

        const float* src = We + ((size_t)e << 20) + (size_t)(kt * 64) * DOUT + ot * 64;
        unsigned short* dst = wt + ((size_t)e << 20) + (size_t)(ot * 64) * DIN + kt * 64;

        int kl = t >> 2;
        int og = (t & 3) * 16;
#pragma unroll
        for (int c = 0; c < 4; ++c) {
            int o = og + c * 4;
            float4 v = *(const float4*)&src[(size_t)kl * DOUT + o];
            ushort4 u;
            u.x = f2bf(v.x); u.y = f2bf(v.y); u.z = f2bf(v.z); u.w = f2bf(v.w);
            *(ushort4*)&tile[kl * 72 + o] = u;
        }
        __syncthreads();
        int ol = t >> 2;
        int kg = (t & 3) * 16;
        unsigned short tmp[16];
#pragma unroll
        for (int i = 0; i < 16; ++i) tmp[i] = tile[(kg + i) * 72 + ol];
        *(uint4*)&dst[(size_t)ol * DIN + kg]     = *(uint4*)&tmp[0];
        *(uint4*)&dst[(size_t)ol * DIN + kg + 8] = *(uint4*)&tmp[8];
    } else {
        // ---- gate branch: 32 tokens per block ----
        float* WgL = smem;          // [8][1024] transposed Wg
        float* xL  = smem + 8192;   // [32][132] x chunk (pad 132 vs 128)
        int n0 = (blockIdx.x - 2048) * 32;

        // stage Wg transposed: 2048 float4 reads, coalesced
#pragma unroll
        for (int q = 0; q < 8; ++q) {
            int fidx = q * 256 + t;          // float4 index 0..2047
            int k  = fidx >> 1;
            int eh = (fidx & 1) * 4;
            float4 v = *(const float4*)&Wg[(size_t)k * 8 + eh];
            WgL[(eh + 0) * 1024 + k] = v.x;
            WgL[(eh + 1) * 1024 + k] = v.y;
            WgL[(eh + 2) * 1024 + k] = v.z;
            WgL[(eh + 3) * 1024 + k] = v.w;
        }

        int tt = t & 31;    // token in block
        int e  = t >> 5;    // expert
        float acc = 0.f;

        for (int c = 0; c < 8; ++c) {
            int kb = c * 128;
            // stage x chunk [32][128] + write bf16 copy
#pragma unroll
            for (int q = 0; q < 4; ++q) {
                int fidx = q * 256 + t;       // float4 idx 0..1023
                int row = fidx >> 5;
                int kk  = (fidx & 31) * 4;
                float4 v = *(const float4*)&x[(size_t)(n0 + row) * DIN + kb + kk];
                ushort4 u;
                u.x = f2bf(v.x); u.y = f2bf(v.y); u.z = f2bf(v.z); u.w = f2bf(v.w);
                *(ushort4*)&xb[(size_t)(n0 + row) * DIN + kb + kk] = u;
                *(float4*)&xL[row * 132 + kk] = v;
            }
            __syncthreads();
#pragma unroll
            for (int kk = 0; kk < 128; kk += 4) {
                float4 xv = *(const float4*)&xL[tt * 132 + kk];
                float4 wv = *(const float4*)&WgL[e * 1024 + kb + kk];
                acc += xv.x * wv.x + xv.y * wv.y + xv.z * wv.z + xv.w * wv.w;
            }
            __syncthreads();
        }

        // softmax across experts per token (logits via LDS)
        float* lg = xL;                 // reuse, post-barrier
        lg[tt * 8 + e] = acc + bg[e];
        __syncthreads();
        if (t < 32) {
            float l[8];
#pragma unroll
            for (int i = 0; i < 8; ++i) l[i] = lg[t * 8 + i];
            float m = l[0];
#pragma unroll
            for (int i = 1; i < 8; ++i) m = fmaxf(m, l[i]);
            float s = 0.f;
#pragma unroll
            for (int i = 0; i < 8; ++i) { l[i] = __expf(l[i] - m); s += l[i]; }
            float inv = 1.0f / s;
            float4 p0 = make_float4(l[0]*inv, l[1]*inv, l[2]*inv, l[3]*inv);
            float4 p1 = make_float4(l[4]*inv, l[5]*inv, l[6]*inv, l[7]*inv);
            *(float4*)&g[(size_t)(n0 + t) * 8]     = p0;
            *(float4*)&g[(size_t)(n0 + t) * 8 + 4] = p1;
        }
    }
}

// ---------------------------------------------------------------------------
// Main MoE GEMM: out[n,o] = sum_e g[n,e] * ((xb @ WebT[e]^T)[n,o] + be[e,o])
// R3 changes vs R2:
//  - BK 64 -> 128: halves barrier count (128 -> 64 windows). LDS = lA+lB =
//    65536 B exactly; g/bias moved to L1-hot global reads in the merge.
//    Occupancy stays 2 blocks/CU (was register-bound anyway) -> avoids
//    m132's 3->2 occupancy regression mode.
//  - 16x16x32 -> 32x32x16 MFMA (2x2 tiles/wave): ~15% better MFMA rate,
//    half the MFMA instruction count.
// Kept from R2 (both verified by counters):
//  - XOR k-chunk swizzle (conflicts 5.1e7 -> 5e5)
//  - XCD-aware bm-slab mapping (FETCH 534 -> 95 MB)
// ---------------------------------------------------------------------------
__global__ __launch_bounds__(256, 2) void moe_gemm_kernel(
    const unsigned short* __restrict__ xb,   // [NTOK][DIN] bf16
    const unsigned short* __restrict__ wt,   // [E][DOUT][DIN] bf16
    const float* __restrict__ g,             // [NTOK][E]
    const float* __restrict__ be,            // [E][DOUT]
    float* __restrict__ out)                 // [NTOK][DOUT]
{
    __shared__ unsigned short lA[128 * 128];   // 32 KB
    __shared__ unsigned short lB[128 * 128];   // 32 KB

    int bid = blockIdx.x;
    int bm = (bid & 7) * 8 + ((bid >> 3) & 7);   // 0..63, XCD-local slab
    int bn = bid >> 6;                            // 0..7
    int tid = threadIdx.x;
    int lane = tid & 63;
    int wave = tid >> 6;
    int wm = wave >> 1;        // 0..1
    int wn = wave & 1;         // 0..1

    const unsigned short* aBase = xb + (size_t)(bm * 128) * DIN;
    const unsigned short* bBase0 = wt + (size_t)(bn * 128) * DIN;

    // staging geometry: instr s covers rows R0..R0+3, R0 = s*16 + wave*4
    int lrow  = lane >> 4;                           // 0..3
    int cphys = lane & 15;                           // physical 16B chunk
    int row7  = (((wave & 1) * 4) + lrow) & 7;       // (R0+lrow)&7
    int clog  = cphys ^ row7;                        // swizzled source chunk

    int col  = lane & 31;
    int half = lane >> 5;

    f32x16 outAcc[2][2] = {};

#pragma unroll 1
    for (int e = 0; e < NEXP; ++e) {
        f32x16 acc[2][2] = {};
        const unsigned short* bBase = bBase0 + ((size_t)e << 20);

#pragma unroll 1
        for (int kt = 0; kt < 8; ++kt) {
            int kb = kt * 128;
            __syncthreads();
#pragma unroll
            for (int s = 0; s < 8; ++s) {
                int R0 = s * 16 + wave * 4;
                size_t srcOff = (size_t)(R0 + lrow) * DIN + kb + clog * 8;
                cp16(aBase + srcOff, &lA[R0 * 128]);
                cp16(bBase + srcOff, &lB[R0 * 128]);
            }
            __syncthreads();
#pragma unroll
            for (int ks = 0; ks < 8; ++ks) {
                int cl = ks * 2 + half;               // logical chunk 0..15
                bf16x8 af[2], bfr[2];
#pragma unroll
                for (int i = 0; i < 2; ++i) {
                    int m = wm * 64 + i * 32 + col;
                    af[i] = *(const bf16x8*)&lA[m * 128 + (cl ^ (m & 7)) * 8];
                }
#pragma unroll
                for (int j = 0; j < 2; ++j) {
                    int o = wn * 64 + j * 32 + col;
                    bfr[j] = *(const bf16x8*)&lB[o * 128 + (cl ^ (o & 7)) * 8];
                }
#pragma unroll
                for (int i = 0; i < 2; ++i)
#pragma unroll
                    for (int j = 0; j < 2; ++j)
                        acc[i][j] = __builtin_amdgcn_mfma_f32_32x32x16_bf16(
                            af[i], bfr[j], acc[i][j], 0, 0, 0);
            }
        }

        // merge: outAcc += g[row,e] * (acc + be[e,col]); g/be L1-hot
        float bv[2];
#pragma unroll
        for (int j = 0; j < 2; ++j)
            bv[j] = be[(size_t)e * DOUT + bn * 128 + wn * 64 + j * 32 + col];
#pragma unroll
        for (int i = 0; i < 2; ++i) {
#pragma unroll
            for (int q = 0; q < 4; ++q) {
                int rbase = bm * 128 + wm * 64 + i * 32 + q * 8 + half * 4;
                float g0 = g[(size_t)(rbase + 0) * 8 + e];
                float g1 = g[(size_t)(rbase + 1) * 8 + e];
                float g2 = g[(size_t)(rbase + 2) * 8 + e];
                float g3 = g[(size_t)(rbase + 3) * 8 + e];
#pragma unroll
                for (int j = 0; j < 2; ++j) {
                    outAcc[i][j][q * 4 + 0] += g0 * (acc[i][j][q * 4 + 0] + bv[j]);
                    outAcc[i][j][q * 4 + 1] += g1 * (acc[i][j][q * 4 + 1] + bv[j]);
                    outAcc[i][j][q * 4 + 2] += g2 * (acc[i][j][q * 4 + 2] + bv[j]);
                    outAcc[i][j][q * 4 + 3] += g3 * (acc[i][j][q * 4 + 3] + bv[j]);
                }
            }
        }
    }

    // epilogue: 32x32 C layout col = lane&31, row = (reg&3) + 8*(reg>>2) + 4*half
#pragma unroll
    for (int i = 0; i < 2; ++i)
#pragma unroll
        for (int q = 0; q < 4; ++q) {
            int row = bm * 128 + wm * 64 + i * 32 + q * 8 + half * 4;
#pragma unroll
            for (int j = 0; j < 2; ++j) {
                int c = bn * 128 + wn * 64 + j * 32 + col;
#pragma unroll
                for (int r = 0; r < 4; ++r)
                    out[(size_t)(row + r) * DOUT + c] = outAcc[i][j][q * 4 + r];
            }
        }
}

// ---------------------------------------------------------------------------
extern "C" void kernel_launch(void* const* d_in, const int* in_sizes, int n_in,
                              void* d_out, int out_size, void* d_ws, size_t ws_size,
                              hipStream_t stream)
{
    const float* x  = (const float*)d_in[0];   // [8192,1024]
    const float* We = (const float*)d_in[1];   // [8,1024,1024]
    const float* be = (const float*)d_in[2];   // [8,1024]
    const float* Wg = (const float*)d_in[3];   // [1024,8]
    const float* bg = (const float*)d_in[4];   // [8]
    float* out = (float*)d_out;                // [8192,1024]

    // workspace: xb (16.78MB bf16) | WebT (16.78MB bf16) | g (256KB f32)
    unsigned short* xb = (unsigned short*)d_ws;
    unsigned short* wt = xb + (size_t)NTOK * DIN;
    float* g = (float*)(wt + (size_t)NEXP * DOUT * DIN);

    prep_kernel<<<2048 + 256, 256, 0, stream>>>(x, We, Wg, bg, xb, wt, g);
    moe_gemm_kernel<<<(NTOK / 128) * (DOUT / 128), 256, 0, stream>>>(xb, wt, g, be, out);
}